// Round 9
// baseline (608.417 us; speedup 1.0000x reference)
//
#include <hip/hip_runtime.h>
#include <hip/hip_bf16.h>
#include <math.h>
#include <stdint.h>

#define BT   4096      // B*T
#define QD   2048      // 2*H*DH
#define DIMK 512       // DIM
#define NH   8
#define DHD  128
#define NKEY 256
#define TK   16

// ---------------------------------------------------------------------------
// fp32 GEMM v2 (no MFMA on CDNA4 for fp32; selection exactness requires fp32
// scores — split-bf16 MFMA was tried in R4-R7 and causes top-k flips).
// 128x128 tile, BK=16, 256 threads, 8x8 micro-tile.
// Double-buffered k-major LDS, ONE barrier per K-tile, global->reg prefetch
// issued before compute (T14).  B-fragment cols {tx*4+j, 64+tx*4+j}:
// 16 lanes x 16B consecutive = 2-way bank alias = free (vs 4-way in R3).
// A-fragment reads are 16-lane broadcast (free).
// ---------------------------------------------------------------------------

// Kernel 1: q = x @ Wq^T (M=4096,N=2048,K=512), fused LayerNorm per 128-col
// (p,h) chunk (tile cols == exactly one chunk; row in 16 tx-lanes).
__global__ __launch_bounds__(256) void qproj_ln(
    const float* __restrict__ x, const float* __restrict__ Wq,
    const float* __restrict__ lng, const float* __restrict__ lnb,
    float* __restrict__ q) {
  __shared__ float As[2][16][128];
  __shared__ float Bs[2][16][128];
  const int br = blockIdx.x;          // m-tile (32)
  const int bc = blockIdx.y;          // n-tile (16) == LN chunk
  const int tid = threadIdx.x;
  const int ty = tid >> 4, tx = tid & 15;
  const int lr = tid >> 1, lc = (tid & 1) * 8;

  const float* xA = x  + (size_t)(br * 128 + lr) * DIMK + lc;
  const float* wB = Wq + (size_t)(bc * 128 + lr) * DIMK + lc;

  float acc[8][8];
  #pragma unroll
  for (int i = 0; i < 8; i++)
    #pragma unroll
    for (int j = 0; j < 8; j++) acc[i][j] = 0.f;

  // prologue: tile 0 -> buf 0
  float4 pa0 = *(const float4*)(xA);
  float4 pa1 = *(const float4*)(xA + 4);
  float4 pb0 = *(const float4*)(wB);
  float4 pb1 = *(const float4*)(wB + 4);
  {
    const float va[8] = {pa0.x,pa0.y,pa0.z,pa0.w,pa1.x,pa1.y,pa1.z,pa1.w};
    const float vb[8] = {pb0.x,pb0.y,pb0.z,pb0.w,pb1.x,pb1.y,pb1.z,pb1.w};
    #pragma unroll
    for (int i = 0; i < 8; i++) { As[0][lc + i][lr] = va[i]; Bs[0][lc + i][lr] = vb[i]; }
  }
  __syncthreads();

  for (int kt = 0; kt < 32; kt++) {
    const int cur = kt & 1;
    const bool more = (kt + 1) < 32;
    if (more) {                      // issue next-tile loads early (T14)
      const int ko = (kt + 1) * 16;
      pa0 = *(const float4*)(xA + ko);
      pa1 = *(const float4*)(xA + ko + 4);
      pb0 = *(const float4*)(wB + ko);
      pb1 = *(const float4*)(wB + ko + 4);
    }
    #pragma unroll
    for (int kk = 0; kk < 16; kk++) {
      float a[8], b[8];
      #pragma unroll
      for (int i = 0; i < 8; i++) a[i] = As[cur][kk][ty * 8 + i];
      #pragma unroll
      for (int j = 0; j < 4; j++) {
        b[j]     = Bs[cur][kk][tx * 4 + j];
        b[4 + j] = Bs[cur][kk][64 + tx * 4 + j];
      }
      #pragma unroll
      for (int i = 0; i < 8; i++)
        #pragma unroll
        for (int j = 0; j < 8; j++)
          acc[i][j] = fmaf(a[i], b[j], acc[i][j]);
    }
    if (more) {                      // write AFTER compute; 1 barrier/tile
      const float va[8] = {pa0.x,pa0.y,pa0.z,pa0.w,pa1.x,pa1.y,pa1.z,pa1.w};
      const float vb[8] = {pb0.x,pb0.y,pb0.z,pb0.w,pb1.x,pb1.y,pb1.z,pb1.w};
      #pragma unroll
      for (int i = 0; i < 8; i++) { As[cur ^ 1][lc + i][lr] = va[i]; Bs[cur ^ 1][lc + i][lr] = vb[i]; }
      __syncthreads();
    }
  }

  // LayerNorm epilogue: row's 128 cols live in the 16 tx-lanes (cols
  // tx*4+j and 64+tx*4+j) -> width-16 shfl_xor reduce.
  float g[8], bb[8];
  #pragma unroll
  for (int j = 0; j < 4; j++) {
    g[j]      = lng[tx * 4 + j];      bb[j]     = lnb[tx * 4 + j];
    g[4 + j]  = lng[64 + tx * 4 + j]; bb[4 + j] = lnb[64 + tx * 4 + j];
  }

  #pragma unroll
  for (int i = 0; i < 8; i++) {
    float s = 0.f;
    #pragma unroll
    for (int j = 0; j < 8; j++) s += acc[i][j];
    #pragma unroll
    for (int m = 1; m < 16; m <<= 1) s += __shfl_xor(s, m);
    const float mu = s * (1.f / 128.f);
    float s2 = 0.f;
    #pragma unroll
    for (int j = 0; j < 8; j++) { const float d = acc[i][j] - mu; s2 = fmaf(d, d, s2); }
    #pragma unroll
    for (int m = 1; m < 16; m <<= 1) s2 += __shfl_xor(s2, m);
    const float rstd = rsqrtf(s2 * (1.f / 128.f) + 1e-5f);
    float o[8];
    #pragma unroll
    for (int j = 0; j < 8; j++)
      o[j] = (acc[i][j] - mu) * rstd * g[j] + bb[j];
    float* qp = q + (size_t)(br * 128 + ty * 8 + i) * QD + bc * 128;
    *(float4*)(qp + tx * 4)      = make_float4(o[0], o[1], o[2], o[3]);
    *(float4*)(qp + 64 + tx * 4) = make_float4(o[4], o[5], o[6], o[7]);
  }
}

// Kernel 2: dots per (h,p): qn @ keys^T (M=4096, N=256, K=128). Same skeleton.
__global__ __launch_bounds__(256) void dots_gemm(
    const float* __restrict__ q, const float* __restrict__ keys,
    float* __restrict__ S) {
  __shared__ float As[2][16][128];
  __shared__ float Bs[2][16][128];
  const int br = blockIdx.x;          // m-tile (32)
  const int bc = blockIdx.y;          // n-tile (2)
  const int hp = blockIdx.z;          // 16
  const int h = hp >> 1, p = hp & 1;
  const int tid = threadIdx.x;
  const int ty = tid >> 4, tx = tid & 15;
  const int lr = tid >> 1, lc = (tid & 1) * 8;

  const float* qA = q + (size_t)(br * 128 + lr) * QD + p * 1024 + h * 128 + lc;
  const float* kB = keys + ((size_t)((h * 256 + bc * 128 + lr) * 2 + p)) * 128 + lc;

  float acc[8][8];
  #pragma unroll
  for (int i = 0; i < 8; i++)
    #pragma unroll
    for (int j = 0; j < 8; j++) acc[i][j] = 0.f;

  float4 pa0 = *(const float4*)(qA);
  float4 pa1 = *(const float4*)(qA + 4);
  float4 pb0 = *(const float4*)(kB);
  float4 pb1 = *(const float4*)(kB + 4);
  {
    const float va[8] = {pa0.x,pa0.y,pa0.z,pa0.w,pa1.x,pa1.y,pa1.z,pa1.w};
    const float vb[8] = {pb0.x,pb0.y,pb0.z,pb0.w,pb1.x,pb1.y,pb1.z,pb1.w};
    #pragma unroll
    for (int i = 0; i < 8; i++) { As[0][lc + i][lr] = va[i]; Bs[0][lc + i][lr] = vb[i]; }
  }
  __syncthreads();

  for (int kt = 0; kt < 8; kt++) {
    const int cur = kt & 1;
    const bool more = (kt + 1) < 8;
    if (more) {
      const int ko = (kt + 1) * 16;
      pa0 = *(const float4*)(qA + ko);
      pa1 = *(const float4*)(qA + ko + 4);
      pb0 = *(const float4*)(kB + ko);
      pb1 = *(const float4*)(kB + ko + 4);
    }
    #pragma unroll
    for (int kk = 0; kk < 16; kk++) {
      float a[8], b[8];
      #pragma unroll
      for (int i = 0; i < 8; i++) a[i] = As[cur][kk][ty * 8 + i];
      #pragma unroll
      for (int j = 0; j < 4; j++) {
        b[j]     = Bs[cur][kk][tx * 4 + j];
        b[4 + j] = Bs[cur][kk][64 + tx * 4 + j];
      }
      #pragma unroll
      for (int i = 0; i < 8; i++)
        #pragma unroll
        for (int j = 0; j < 8; j++)
          acc[i][j] = fmaf(a[i], b[j], acc[i][j]);
    }
    if (more) {
      const float va[8] = {pa0.x,pa0.y,pa0.z,pa0.w,pa1.x,pa1.y,pa1.z,pa1.w};
      const float vb[8] = {pb0.x,pb0.y,pb0.z,pb0.w,pb1.x,pb1.y,pb1.z,pb1.w};
      #pragma unroll
      for (int i = 0; i < 8; i++) { As[cur ^ 1][lc + i][lr] = va[i]; Bs[cur ^ 1][lc + i][lr] = vb[i]; }
      __syncthreads();
    }
  }

  float* Sp = S + (size_t)hp * BT * NKEY;
  #pragma unroll
  for (int i = 0; i < 8; i++) {
    float* pp = Sp + (size_t)(br * 128 + ty * 8 + i) * NKEY + bc * 128;
    *(float4*)(pp + tx * 4)      = make_float4(acc[i][0], acc[i][1], acc[i][2], acc[i][3]);
    *(float4*)(pp + 64 + tx * 4) = make_float4(acc[i][4], acc[i][5], acc[i][6], acc[i][7]);
  }
}

// ---------------------------------------------------------------------------
// Kernel 3: exact top-16 via radix-select (verified round 3, unchanged).
// ---------------------------------------------------------------------------
__device__ __forceinline__ uint32_t f2u(float f) {
  uint32_t b = __float_as_uint(f);
  return b ^ ((uint32_t)((int32_t)b >> 31) | 0x80000000u);
}
__device__ __forceinline__ float u2f(uint32_t u) {
  uint32_t b = (u & 0x80000000u) ? (u ^ 0x80000000u) : ~u;
  return __uint_as_float(b);
}
__device__ __forceinline__ int cnt_lt(uint64_t m) {
  return __builtin_amdgcn_mbcnt_hi((uint32_t)(m >> 32),
         __builtin_amdgcn_mbcnt_lo((uint32_t)m, 0));
}

__global__ __launch_bounds__(64) void topk_combine(
    const float* __restrict__ S, float* __restrict__ W, int* __restrict__ I) {
  const int bt = blockIdx.x;
  const int h  = blockIdx.y;
  const int l  = threadIdx.x;

  __shared__ __align__(16) float sx_lds[16], sy_lds[16], w_lds[16];
  __shared__ __align__(16) int   ix_lds[16], iy_lds[16], vi_lds[16];

  const float* S0 = S + ((size_t)(h * 2 + 0) * BT + bt) * NKEY;
  const float* S1 = S + ((size_t)(h * 2 + 1) * BT + bt) * NKEY;
  float4 v0 = *(const float4*)(S0 + l * 4);
  float4 v1 = *(const float4*)(S1 + l * 4);
  float s0[4] = {v0.x, v0.y, v0.z, v0.w};
  float s1[4] = {v1.x, v1.y, v1.z, v1.w};
  uint32_t u0[4], u1[4];
  #pragma unroll
  for (int r = 0; r < 4; r++) { u0[r] = f2u(s0[r]); u1[r] = f2u(s1[r]); }

  uint32_t pfx0 = 0u, pfx1 = 0u;
  #pragma unroll
  for (int b = 31; b >= 0; b--) {
    const uint32_t t0 = pfx0 | (1u << b);
    const uint32_t t1 = pfx1 | (1u << b);
    int c0 = 0, c1 = 0;
    #pragma unroll
    for (int r = 0; r < 4; r++) {
      c0 += __popcll(__ballot(u0[r] >= t0));
      c1 += __popcll(__ballot(u1[r] >= t1));
    }
    if (c0 >= TK) pfx0 = t0;
    if (c1 >= TK) pfx1 = t1;
  }

  {
    uint64_t mgt[4], meq[4];
    int ngt = 0, below_gt = 0, below_eq = 0;
    #pragma unroll
    for (int r = 0; r < 4; r++) {
      mgt[r] = __ballot(u0[r] > pfx0);
      meq[r] = __ballot(u0[r] == pfx0);
      ngt += __popcll(mgt[r]);
      below_gt += cnt_lt(mgt[r]);
      below_eq += cnt_lt(meq[r]);
    }
    const int need = TK - ngt;
    int loc_gt = 0, loc_eq = 0;
    #pragma unroll
    for (int r = 0; r < 4; r++) {
      const bool isgt = (u0[r] > pfx0), iseq = (u0[r] == pfx0);
      int slot = -1;
      if (isgt) slot = below_gt + loc_gt;
      else if (iseq) { const int re = below_eq + loc_eq; if (re < need) slot = ngt + re; }
      if (slot >= 0) { sx_lds[slot] = s0[r]; ix_lds[slot] = l * 4 + r; }
      loc_gt += isgt; loc_eq += iseq;
    }
  }
  {
    uint64_t mgt[4], meq[4];
    int ngt = 0, below_gt = 0, below_eq = 0;
    #pragma unroll
    for (int r = 0; r < 4; r++) {
      mgt[r] = __ballot(u1[r] > pfx1);
      meq[r] = __ballot(u1[r] == pfx1);
      ngt += __popcll(mgt[r]);
      below_gt += cnt_lt(mgt[r]);
      below_eq += cnt_lt(meq[r]);
    }
    const int need = TK - ngt;
    int loc_gt = 0, loc_eq = 0;
    #pragma unroll
    for (int r = 0; r < 4; r++) {
      const bool isgt = (u1[r] > pfx1), iseq = (u1[r] == pfx1);
      int slot = -1;
      if (isgt) slot = below_gt + loc_gt;
      else if (iseq) { const int re = below_eq + loc_eq; if (re < need) slot = ngt + re; }
      if (slot >= 0) { sy_lds[slot] = s1[r]; iy_lds[slot] = l * 4 + r; }
      loc_gt += isgt; loc_eq += iseq;
    }
  }
  __syncthreads();

  const float sxv = sx_lds[l >> 2];
  const float4 syv = *(const float4*)&sy_lds[(l & 3) * 4];
  float cv[4] = {sxv + syv.x, sxv + syv.y, sxv + syv.z, sxv + syv.w};
  uint32_t uc[4];
  #pragma unroll
  for (int r = 0; r < 4; r++) uc[r] = f2u(cv[r]);

  uint32_t pfx2 = 0u;
  #pragma unroll
  for (int b = 31; b >= 0; b--) {
    const uint32_t t2 = pfx2 | (1u << b);
    int c2 = 0;
    #pragma unroll
    for (int r = 0; r < 4; r++) c2 += __popcll(__ballot(uc[r] >= t2));
    if (c2 >= TK) pfx2 = t2;
  }

  const float tau2f = u2f(pfx2);
  const int ivx = ix_lds[l >> 2];
  const int4 iyv = *(const int4*)&iy_lds[(l & 3) * 4];
  const int iy4[4] = {iyv.x, iyv.y, iyv.z, iyv.w};
  {
    uint64_t mgt[4], meq[4];
    int ngt = 0, below_gt = 0, below_eq = 0;
    #pragma unroll
    for (int r = 0; r < 4; r++) {
      mgt[r] = __ballot(uc[r] > pfx2);
      meq[r] = __ballot(uc[r] == pfx2);
      ngt += __popcll(mgt[r]);
      below_gt += cnt_lt(mgt[r]);
      below_eq += cnt_lt(meq[r]);
    }
    const int need = TK - ngt;
    int loc_gt = 0, loc_eq = 0;
    #pragma unroll
    for (int r = 0; r < 4; r++) {
      const bool isgt = (uc[r] > pfx2), iseq = (uc[r] == pfx2);
      int slot = -1;
      if (isgt) slot = below_gt + loc_gt;
      else if (iseq) { const int re = below_eq + loc_eq; if (re < need) slot = ngt + re; }
      if (slot >= 0) {
        w_lds[slot]  = __expf(cv[r] - tau2f);
        vi_lds[slot] = ivx * NKEY + iy4[r];
      }
      loc_gt += isgt; loc_eq += iseq;
    }
  }
  __syncthreads();

  if (l < TK) {
    const float4 wa = *(const float4*)&w_lds[0];
    const float4 wb = *(const float4*)&w_lds[4];
    const float4 wc = *(const float4*)&w_lds[8];
    const float4 wd = *(const float4*)&w_lds[12];
    const float sum = (wa.x + wa.y + wa.z + wa.w) + (wb.x + wb.y + wb.z + wb.w)
                    + (wc.x + wc.y + wc.z + wc.w) + (wd.x + wd.y + wd.z + wd.w);
    const size_t o = ((size_t)bt * NH + h) * TK + l;
    W[o] = w_lds[l] / sum;
    I[o] = vi_lds[l];
  }
}

// ---------------------------------------------------------------------------
// Kernel 4: out[bt,:] = sum_{r<128} w[bt,r] * values[idx[bt,r], :]  (unchanged;
// measured 160 us at ~6.7 TB/s effective L3+HBM — at the bandwidth roofline)
// ---------------------------------------------------------------------------
__global__ __launch_bounds__(128) void gather_out(
    const float* __restrict__ values, const float* __restrict__ W,
    const int* __restrict__ I, float* __restrict__ out) {
  const int bt = blockIdx.x;
  const int t  = threadIdx.x;
  __shared__ float wsm[128];
  __shared__ int   ism[128];
  wsm[t] = W[(size_t)bt * 128 + t];
  ism[t] = I[(size_t)bt * 128 + t];
  __syncthreads();
  float4 acc = make_float4(0.f, 0.f, 0.f, 0.f);
  #pragma unroll 4
  for (int r = 0; r < 128; r++) {
    const float w = wsm[r];
    const float4 v = *(const float4*)(values + (size_t)ism[r] * DIMK + t * 4);
    acc.x = fmaf(w, v.x, acc.x);
    acc.y = fmaf(w, v.y, acc.y);
    acc.z = fmaf(w, v.z, acc.z);
    acc.w = fmaf(w, v.w, acc.w);
  }
  *(float4*)(out + (size_t)bt * DIMK + t * 4) = acc;
}

// ---------------------------------------------------------------------------
extern "C" void kernel_launch(void* const* d_in, const int* in_sizes, int n_in,
                              void* d_out, int out_size, void* d_ws, size_t ws_size,
                              hipStream_t stream) {
  const float* x      = (const float*)d_in[0];
  const float* Wq     = (const float*)d_in[1];
  const float* lng    = (const float*)d_in[2];
  const float* lnb    = (const float*)d_in[3];
  const float* keys   = (const float*)d_in[4];
  const float* values = (const float*)d_in[5];
  float* out = (float*)d_out;

  char* ws = (char*)d_ws;
  const size_t MB = 1024 * 1024;
  float* q = (float*)(ws);                     // 32 MB
  float* S = (float*)(ws + 32 * MB);           // 64 MB
  float* W = (float*)(ws + 96 * MB);           //  2 MB
  int*   I = (int*)  (ws + 98 * MB);           //  2 MB

  qproj_ln    <<<dim3(32, 16),    256, 0, stream>>>(x, Wq, lng, lnb, q);
  dots_gemm   <<<dim3(32, 2, 16), 256, 0, stream>>>(q, keys, S);
  topk_combine<<<dim3(4096, 8),   64,  0, stream>>>(S, W, I);
  gather_out  <<<dim3(4096),      128, 0, stream>>>(values, W, I, out);
}